// Round 10
// baseline (144.318 us; speedup 1.0000x reference)
//
#include <hip/hip_runtime.h>
#include <hip/hip_bf16.h>
#include <math.h>

#define NR 4096
#define NS 768

// Outputs (flat, fp32): depth[4096] | image[4096*2] | wsum[4096] | weights[4096*768] | z_vals[4096*768]
#define OFF_IMAGE   (NR)
#define OFF_WSUM    (NR*3)
#define OFF_WEIGHTS (NR*4)
#define OFF_ZVALS   (NR*4 + NR*NS)

typedef short bf16x8 __attribute__((ext_vector_type(8)));
typedef float f32x4  __attribute__((ext_vector_type(4)));

static __device__ __forceinline__ unsigned cvt_pk_bf16(float a, float b){
    unsigned r;
    asm("v_cvt_pk_bf16_f32 %0, %1, %2" : "=v"(r) : "v"(a), "v"(b));
    return r;
}
static __device__ __forceinline__ f32x4 zero4(){ f32x4 r = {0.f,0.f,0.f,0.f}; return r; }
// zero-instruction compiler fence: pins LDS write<->read program order across
// the uint2-store / short8-load TBAA gap (r9 NaN root-cause hypothesis).
static __device__ __forceinline__ void ldsfence(){ asm volatile("" ::: "memory"); }

// ---------------------------------------------------------------------------
// Slab-form transposed MLP (r8 dataflow, 16-sample slabs, r9 + fences):
// 4 independent 16-column slabs per wave-tile, acc = f32x4[4] (16 regs),
// bounce 2 KB/wave, LDS 24 KB/block, __launch_bounds__(256,3) -> 3 blocks/CU.
// Bounce addressing (HW-verified in r8): write word c*8+g*2 + ft*128 (b64);
// read word (g>>1)*128 + c*8 + (g&1)*4 + kt*256 (b128).
// relu = fmaxf pair + cvt_pk (r8-proven form).
// ---------------------------------------------------------------------------
__global__ __launch_bounds__(256, 3) void mlp_mfma_kernel(
    const float* __restrict__ rays_o, const float* __restrict__ rays_d,
    const float* __restrict__ timev,
    const float* __restrict__ W1, const float* __restrict__ b1,
    const float* __restrict__ W2, const float* __restrict__ b2,
    const float* __restrict__ w_sig, const float* __restrict__ b_sig,
    const float* __restrict__ Wc1, const float* __restrict__ bc1,
    const float* __restrict__ Wc2, const float* __restrict__ bc2,
    float* __restrict__ alpha_out,   // [NR*NS] (aliases weights slot of d_out)
    float* __restrict__ rgb_out)     // [NR*NS][2] in d_ws
{
    __shared__ __align__(16) unsigned bounce[4][512];      // 2 KB per wave
    __shared__ __align__(16) unsigned stash[16*64*4];      // 16 frag slots
    const int wid  = threadIdx.x >> 6;
    const int lane = threadIdx.x & 63;
    const int g = lane >> 4;          // 0..3
    const int c = lane & 15;          // 0..15

    // ---- stash (block-shared, built by wave 0) — identical to r8 ----
    if (wid == 0) {
        #pragma unroll
        for (int ft = 0; ft < 4; ++ft) {
            const int col = ft*16 + c;
            unsigned u0=0,u1=0,u2=0,u3=0, d0=0,d1=0;
            if (g == 0) {
                u0 = cvt_pk_bf16(W1[0*64+col], W1[1*64+col]);
                u1 = cvt_pk_bf16(W1[2*64+col], W1[3*64+col]);
                u2 = cvt_pk_bf16(b1[col], 0.f);
                d0 = cvt_pk_bf16(Wc1[0*64+col], Wc1[1*64+col]);
                d1 = cvt_pk_bf16(Wc1[2*64+col], bc1[col]);
            }
            unsigned* p = &stash[(ft*64 + lane)*4];
            p[0]=u0; p[1]=u1; p[2]=u2; p[3]=u3;
            unsigned* q = &stash[((4+ft)*64 + lane)*4];
            q[0]=d0; q[1]=d1; q[2]=0; q[3]=0;
        }
        #pragma unroll
        for (int kt = 0; kt < 2; ++kt) {
            unsigned s[4], w[4];
            #pragma unroll
            for (int p = 0; p < 4; ++p) {
                int k = kt*32 + 8*g + 2*p;
                s[p] = (c == 0) ? cvt_pk_bf16(w_sig[k], w_sig[k+1]) : 0u;
                w[p] = (c < 2)  ? cvt_pk_bf16(Wc2[k*2+c], Wc2[(k+1)*2+c]) : 0u;
            }
            unsigned* ps = &stash[((8+kt)*64 + lane)*4];
            ps[0]=s[0]; ps[1]=s[1]; ps[2]=s[2]; ps[3]=s[3];
            unsigned* pw = &stash[((10+kt)*64 + lane)*4];
            pw[0]=w[0]; pw[1]=w[1]; pw[2]=w[2]; pw[3]=w[3];
        }
        #pragma unroll
        for (int ft = 0; ft < 4; ++ft) {
            float* pb = reinterpret_cast<float*>(&stash[((12+ft)*64 + lane)*4]);
            #pragma unroll
            for (int r = 0; r < 4; ++r) pb[r] = b2[ft*16 + g*4 + r];
        }
    }

    // ---- hot A-frags in registers ----
    auto ldfrag = [&](const float* __restrict__ W, int k0, int col)->bf16x8 {
        union { bf16x8 v; unsigned u[4]; } r;
        #pragma unroll
        for (int p = 0; p < 4; ++p) {
            int k = k0 + 2*p;
            r.u[p] = cvt_pk_bf16(W[k*64 + col], W[(k+1)*64 + col]);
        }
        return r.v;
    };
    bf16x8 bW2A[2][4], bWc1A[2][4];
    #pragma unroll
    for (int ft = 0; ft < 4; ++ft) {
        const int col = ft*16 + c;
        #pragma unroll
        for (int kt = 0; kt < 2; ++kt) {
            bW2A[kt][ft]  = ldfrag(W2,         kt*32 + 8*g, col);
            bWc1A[kt][ft] = ldfrag(Wc1 + 3*64, kt*32 + 8*g, col);
        }
    }
    const float bsg = b_sig[0];
    f32x4 bc2v;
    bc2v[0] = (g==0) ? bc2[0] : 0.f;
    bc2v[1] = (g==0) ? bc2[1] : 0.f;
    bc2v[2] = 0.f; bc2v[3] = 0.f;

    __syncthreads();

    unsigned* BW = &bounce[wid][0];
    const int wbase = c*8 + g*2;                         // write word base
    const int rbase = (g>>1)*128 + c*8 + (g&1)*4;        // read word base
    auto SL = [&](int s)->bf16x8 {
        return *reinterpret_cast<const bf16x8*>(&stash[(s*64 + lane)*4]);
    };
    // relu+pack+store one acc tile to bounce slot ft (fenced by caller)
    auto BOUNCE = [&](const f32x4& a, int ft){
        unsigned pk0 = cvt_pk_bf16(fmaxf(a[0],0.f), fmaxf(a[1],0.f));
        unsigned pk1 = cvt_pk_bf16(fmaxf(a[2],0.f), fmaxf(a[3],0.f));
        *reinterpret_cast<uint2*>(&BW[wbase + ft*128]) = make_uint2(pk0, pk1);
    };

    const int gwave = blockIdx.x*4 + wid;

    #pragma unroll 1
    for (int tt = 0; tt < 4; ++tt) {
        const int tile = gwave*4 + tt;          // 0..49151
        const int n  = tile / 12;               // ray (wave-uniform)
        const int s0 = (tile - n*12) * 64;
        const int s  = s0 + lane;               // this lane's sample (step idx)

        const float z  = 0.01f + 0.8f * ((float)s * (1.0f/767.0f));
        const float ox = rays_o[3*n+0], oy = rays_o[3*n+1], oz = rays_o[3*n+2];
        const float dx = rays_d[3*n+0], dy = rays_d[3*n+1], dz = rays_d[3*n+2];
        const float tm = timev[n];

        const float px = fminf(fmaxf(fmaf(dx, z, ox), -1.f), 1.f);
        const float py = fminf(fmaxf(fmaf(dy, z, oy), -1.f), 1.f);
        const float pz = fminf(fmaxf(fmaf(dz, z, oz), -1.f), 1.f);
        const unsigned p01 = cvt_pk_bf16(px, py);
        const unsigned p23 = cvt_pk_bf16(pz, tm);

        // dirs+bias B-frag for GEMM3's 3rd k-step (tile-invariant)
        union { bf16x8 v; unsigned u[4]; } fd;
        fd.u[0] = (g==0) ? cvt_pk_bf16(dx, dy) : 0u;
        fd.u[1] = (g==0) ? cvt_pk_bf16(dz, 1.0f) : 0u;
        fd.u[2] = 0u; fd.u[3] = 0u;

        float sg[4], rg0[4], rg1[4];

        #pragma unroll
        for (int sl = 0; sl < 4; ++sl) {
            f32x4 acc[4];

            // ---- GEMM1: W1ext^T @ X^T slab (K=32, bias at k=4) ----
            {
                unsigned q0 = (unsigned)__shfl((int)p01, sl*16 + c);
                unsigned q1 = (unsigned)__shfl((int)p23, sl*16 + c);
                union { bf16x8 v; unsigned u[4]; } b;
                b.u[0] = (g==0) ? q0 : 0u;
                b.u[1] = (g==0) ? q1 : 0u;
                b.u[2] = (g==0) ? 0x00003F80u : 0u;   // bf16 1.0 at k=4
                b.u[3] = 0u;
                #pragma unroll
                for (int ft = 0; ft < 4; ++ft)
                    acc[ft] = __builtin_amdgcn_mfma_f32_16x16x32_bf16(
                        SL(ft), b.v, zero4(), 0, 0, 0);
            }
            ldsfence();
            #pragma unroll
            for (int ft = 0; ft < 4; ++ft) BOUNCE(acc[ft], ft);   // h1
            ldsfence();

            // ---- GEMM2: W2^T @ h1 (C-init = b2 from stash) ----
            {
                bf16x8 f0 = *reinterpret_cast<const bf16x8*>(&BW[rbase]);
                bf16x8 f1 = *reinterpret_cast<const bf16x8*>(&BW[rbase + 256]);
                ldsfence();
                #pragma unroll
                for (int ft = 0; ft < 4; ++ft) {
                    f32x4 b2v = *reinterpret_cast<const f32x4*>(&stash[((12+ft)*64 + lane)*4]);
                    f32x4 d = __builtin_amdgcn_mfma_f32_16x16x32_bf16(bW2A[0][ft], f0, b2v, 0,0,0);
                    acc[ft]  = __builtin_amdgcn_mfma_f32_16x16x32_bf16(bW2A[1][ft], f1, d, 0,0,0);
                }
            }
            ldsfence();
            #pragma unroll
            for (int ft = 0; ft < 4; ++ft) BOUNCE(acc[ft], ft);   // h2
            ldsfence();

            // ---- GEMM3: Wc1^T @ [h2; dirs; 1] + sigma ride-along ----
            {
                bf16x8 f0 = *reinterpret_cast<const bf16x8*>(&BW[rbase]);
                bf16x8 f1 = *reinterpret_cast<const bf16x8*>(&BW[rbase + 256]);
                ldsfence();
                #pragma unroll
                for (int ft = 0; ft < 4; ++ft) {
                    f32x4 d = __builtin_amdgcn_mfma_f32_16x16x32_bf16(bWc1A[0][ft], f0, zero4(), 0,0,0);
                    d = __builtin_amdgcn_mfma_f32_16x16x32_bf16(bWc1A[1][ft], f1, d, 0,0,0);
                    acc[ft] = __builtin_amdgcn_mfma_f32_16x16x32_bf16(SL(4+ft), fd.v, d, 0,0,0);
                }
                f32x4 sd = __builtin_amdgcn_mfma_f32_16x16x32_bf16(SL(8), f0, zero4(), 0,0,0);
                sd = __builtin_amdgcn_mfma_f32_16x16x32_bf16(SL(9), f1, sd, 0,0,0);
                sg[sl] = sd[0];
            }
            ldsfence();
            #pragma unroll
            for (int ft = 0; ft < 4; ++ft) BOUNCE(acc[ft], ft);   // cfeat
            ldsfence();

            // ---- GEMM4: Wc2^T @ cfeat (rows 0,1) ----
            {
                bf16x8 f0 = *reinterpret_cast<const bf16x8*>(&BW[rbase]);
                bf16x8 f1 = *reinterpret_cast<const bf16x8*>(&BW[rbase + 256]);
                ldsfence();
                f32x4 d = __builtin_amdgcn_mfma_f32_16x16x32_bf16(SL(10), f0, bc2v, 0,0,0);
                d = __builtin_amdgcn_mfma_f32_16x16x32_bf16(SL(11), f1, d, 0,0,0);
                rg0[sl] = d[0];
                rg1[sl] = d[1];
            }
        }

        // ---- sigma redistribute + alpha (valid data in lanes g==0) ----
        {
            float v0 = __shfl(sg[0], c);
            float v1 = __shfl(sg[1], c);
            float v2 = __shfl(sg[2], c);
            float v3 = __shfl(sg[3], c);
            float pre = (g==0) ? v0 : ((g==1) ? v1 : ((g==2) ? v2 : v3));
            pre += bsg;
            float sig = fmaxf(pre, 0.f) + __logf(1.f + __expf(-fabsf(pre)));
            float dl  = (s == NS-1) ? (0.8f/768.0f) : (0.8f/767.0f);
            alpha_out[tile*64 + lane] = 1.0f - __expf(-dl * sig);
        }
        // ---- rgb redistribute + sigmoid ----
        {
            float a0 = __shfl(rg0[0], c), b0 = __shfl(rg1[0], c);
            float a1 = __shfl(rg0[1], c), b1v_ = __shfl(rg1[1], c);
            float a2 = __shfl(rg0[2], c), b2_ = __shfl(rg1[2], c);
            float a3 = __shfl(rg0[3], c), b3 = __shfl(rg1[3], c);
            float r0 = (g==0) ? a0 : ((g==1) ? a1 : ((g==2) ? a2 : a3));
            float r1 = (g==0) ? b0 : ((g==1) ? b1v_ : ((g==2) ? b2_ : b3));
            r0 = 1.0f / (1.0f + __expf(-r0));
            r1 = 1.0f / (1.0f + __expf(-r1));
            *reinterpret_cast<float2*>(&rgb_out[2*(tile*64 + lane)]) = make_float2(r0, r1);
        }
    }
}

// ---------------------------------------------------------------------------
// Kernel 2: wave-per-ray compositing (unchanged, proven correct)
// ---------------------------------------------------------------------------
__global__ __launch_bounds__(256) void composite_kernel(
    const float* __restrict__ rgb,   // [NR][NS][2]
    float* __restrict__ out)
{
    int gtid = blockIdx.x * 256 + threadIdx.x;
    int ray  = gtid >> 6;
    int lane = threadIdx.x & 63;
    if (ray >= NR) return;

    float* __restrict__ depth_o = out;
    float* __restrict__ image_o = out + OFF_IMAGE;
    float* __restrict__ wsum_o  = out + OFF_WSUM;
    float* __restrict__ w_o     = out + OFF_WEIGHTS;   // alpha in, weights out
    float* __restrict__ z_o     = out + OFF_ZVALS;

    float T = 1.0f;
    float depth = 0.0f, wsum = 0.0f, im0 = 0.0f, im1 = 0.0f;

    for (int ch = 0; ch < NS/64; ++ch) {
        int s   = ch*64 + lane;
        int idx = ray*NS + s;
        float a  = w_o[idx];
        float zv = 0.01f + 0.8f * ((float)s * (1.0f/767.0f));
        float f  = 1.0f - a + 1e-15f;

        float p = f;
        #pragma unroll
        for (int off = 1; off < 64; off <<= 1) {
            float v = __shfl_up(p, off, 64);
            if (lane >= off) p *= v;
        }
        float excl = __shfl_up(p, 1, 64);
        if (lane == 0) excl = 1.0f;

        float wgt = a * T * excl;

        float r0 = rgb[2*idx + 0], r1 = rgb[2*idx + 1];
        depth = fmaf(wgt, zv, depth);
        wsum += wgt;
        im0   = fmaf(wgt, r0, im0);
        im1   = fmaf(wgt, r1, im1);

        w_o[idx] = wgt;
        z_o[idx] = zv;

        T *= __shfl(p, 63, 64);
    }

    #pragma unroll
    for (int off = 32; off >= 1; off >>= 1) {
        depth += __shfl_down(depth, off, 64);
        wsum  += __shfl_down(wsum , off, 64);
        im0   += __shfl_down(im0  , off, 64);
        im1   += __shfl_down(im1  , off, 64);
    }
    if (lane == 0) {
        depth_o[ray]      = depth;
        image_o[2*ray+0]  = im0;
        image_o[2*ray+1]  = im1;
        wsum_o[ray]       = wsum;
    }
}

extern "C" void kernel_launch(void* const* d_in, const int* in_sizes, int n_in,
                              void* d_out, int out_size, void* d_ws, size_t ws_size,
                              hipStream_t stream) {
    const float* rays_o = (const float*)d_in[0];
    const float* rays_d = (const float*)d_in[1];
    const float* timev  = (const float*)d_in[2];
    const float* W1     = (const float*)d_in[3];
    const float* b1     = (const float*)d_in[4];
    const float* W2     = (const float*)d_in[5];
    const float* b2     = (const float*)d_in[6];
    const float* w_sig  = (const float*)d_in[7];
    const float* b_sig  = (const float*)d_in[8];
    const float* Wc1    = (const float*)d_in[9];
    const float* bc1    = (const float*)d_in[10];
    const float* Wc2    = (const float*)d_in[11];
    const float* bc2    = (const float*)d_in[12];

    float* out   = (float*)d_out;
    float* alpha = out + OFF_WEIGHTS;      // stash alpha in the weights slot
    float* rgb   = (float*)d_ws;           // [NR][NS][2] fp32

    dim3 blk(256);
    // 3072 blocks * 4 waves * 4 tiles * 64 samples = 4096*768 samples
    hipLaunchKernelGGL(mlp_mfma_kernel, dim3(3072), blk, 0, stream,
                       rays_o, rays_d, timev, W1, b1, W2, b2, w_sig, b_sig,
                       Wc1, bc1, Wc2, bc2, alpha, rgb);

    hipLaunchKernelGGL(composite_kernel, dim3((NR*64)/256), blk, 0, stream, rgb, out);
}

// Round 11
// 138.851 us; speedup vs baseline: 1.0394x; 1.0394x over previous
//
#include <hip/hip_runtime.h>
#include <hip/hip_bf16.h>
#include <math.h>

#define NR 4096
#define NS 768

// Outputs (flat, fp32): depth[4096] | image[4096*2] | wsum[4096] | weights[4096*768] | z_vals[4096*768]
#define OFF_IMAGE   (NR)
#define OFF_WSUM    (NR*3)
#define OFF_WEIGHTS (NR*4)
#define OFF_ZVALS   (NR*4 + NR*NS)

typedef short bf16x8 __attribute__((ext_vector_type(8)));
typedef float f32x4  __attribute__((ext_vector_type(4)));

static __device__ __forceinline__ unsigned cvt_pk_bf16(float a, float b){
    unsigned r;
    asm("v_cvt_pk_bf16_f32 %0, %1, %2" : "=v"(r) : "v"(a), "v"(b));
    return r;
}
// relu on 2 packed bf16: positive bf16 are order-isomorphic to positive i16,
// negatives (sign bit set) are negative i16 -> max_i16(x,0) zeroes them.
// Cannot produce NaN: output is either the finite input or +0.
static __device__ __forceinline__ unsigned pk_relu_bf16x2(unsigned x){
    unsigned r;
    asm("v_pk_max_i16 %0, %1, 0" : "=v"(r) : "v"(x));
    return r;
}
static __device__ __forceinline__ float bf2f(unsigned short h){
    return __builtin_bit_cast(float, ((unsigned)h) << 16);
}
static __device__ __forceinline__ f32x4 zero4(){ f32x4 r = {0.f,0.f,0.f,0.f}; return r; }
// zero-instruction compiler fence: pins LDS write<->read program order across
// the uint2-store / short8-load TBAA gap (r9 NaN root cause, r10-proven fix).
static __device__ __forceinline__ void ldsfence(){ asm volatile("" ::: "memory"); }

// ---------------------------------------------------------------------------
// Full-tile transposed MLP (r8 structure, 124 us proven) + r10 fences +
// pk_relu + packed-bf16 rgb + setprio around MFMA clusters.
// Bounce addressing (HW-verified r8): write word c*8+g*2 + (nt*4+ft)*128 (b64);
// read word (g>>1)*128 + c*8 + (g&1)*4 + (nt*4+kt*2)*128 (b128).
// ---------------------------------------------------------------------------
__global__ __launch_bounds__(256, 2) void mlp_mfma_kernel(
    const float* __restrict__ rays_o, const float* __restrict__ rays_d,
    const float* __restrict__ timev,
    const float* __restrict__ W1, const float* __restrict__ b1,
    const float* __restrict__ W2, const float* __restrict__ b2,
    const float* __restrict__ w_sig, const float* __restrict__ b_sig,
    const float* __restrict__ Wc1, const float* __restrict__ bc1,
    const float* __restrict__ Wc2, const float* __restrict__ bc2,
    float* __restrict__ alpha_out,     // [NR*NS] (aliases weights slot of d_out)
    unsigned* __restrict__ rgb_out)    // [NR*NS] packed 2xbf16 in d_ws
{
    __shared__ __align__(16) unsigned bounce[4][2048];     // 8 KB per wave
    __shared__ __align__(16) unsigned stash[16*64*4];      // 16 frag slots
    const int wid  = threadIdx.x >> 6;
    const int lane = threadIdx.x & 63;
    const int g = lane >> 4;          // 0..3
    const int c = lane & 15;          // 0..15

    // ---- stash (block-shared, built by wave 0) ----
    if (wid == 0) {
        #pragma unroll
        for (int ft = 0; ft < 4; ++ft) {
            const int col = ft*16 + c;
            unsigned u0=0,u1=0,u2=0,u3=0, d0=0,d1=0;
            if (g == 0) {
                u0 = cvt_pk_bf16(W1[0*64+col], W1[1*64+col]);
                u1 = cvt_pk_bf16(W1[2*64+col], W1[3*64+col]);
                u2 = cvt_pk_bf16(b1[col], 0.f);
                d0 = cvt_pk_bf16(Wc1[0*64+col], Wc1[1*64+col]);
                d1 = cvt_pk_bf16(Wc1[2*64+col], bc1[col]);
            }
            unsigned* p = &stash[(ft*64 + lane)*4];
            p[0]=u0; p[1]=u1; p[2]=u2; p[3]=u3;
            unsigned* q = &stash[((4+ft)*64 + lane)*4];
            q[0]=d0; q[1]=d1; q[2]=0; q[3]=0;
        }
        #pragma unroll
        for (int kt = 0; kt < 2; ++kt) {
            unsigned s[4], w[4];
            #pragma unroll
            for (int p = 0; p < 4; ++p) {
                int k = kt*32 + 8*g + 2*p;
                s[p] = (c == 0) ? cvt_pk_bf16(w_sig[k], w_sig[k+1]) : 0u;
                w[p] = (c < 2)  ? cvt_pk_bf16(Wc2[k*2+c], Wc2[(k+1)*2+c]) : 0u;
            }
            unsigned* ps = &stash[((8+kt)*64 + lane)*4];
            ps[0]=s[0]; ps[1]=s[1]; ps[2]=s[2]; ps[3]=s[3];
            unsigned* pw = &stash[((10+kt)*64 + lane)*4];
            pw[0]=w[0]; pw[1]=w[1]; pw[2]=w[2]; pw[3]=w[3];
        }
        #pragma unroll
        for (int ft = 0; ft < 4; ++ft) {
            float* pb = reinterpret_cast<float*>(&stash[((12+ft)*64 + lane)*4]);
            #pragma unroll
            for (int r = 0; r < 4; ++r) pb[r] = b2[ft*16 + g*4 + r];
        }
    }

    // ---- hot A-frags in registers ----
    auto ldfrag = [&](const float* __restrict__ W, int k0, int col)->bf16x8 {
        union { bf16x8 v; unsigned u[4]; } r;
        #pragma unroll
        for (int p = 0; p < 4; ++p) {
            int k = k0 + 2*p;
            r.u[p] = cvt_pk_bf16(W[k*64 + col], W[(k+1)*64 + col]);
        }
        return r.v;
    };
    bf16x8 bW2A[2][4], bWc1A[2][4];
    #pragma unroll
    for (int ft = 0; ft < 4; ++ft) {
        const int col = ft*16 + c;
        #pragma unroll
        for (int kt = 0; kt < 2; ++kt) {
            bW2A[kt][ft]  = ldfrag(W2,         kt*32 + 8*g, col);
            bWc1A[kt][ft] = ldfrag(Wc1 + 3*64, kt*32 + 8*g, col);
        }
    }
    const float bsg = b_sig[0];
    f32x4 bc2v;
    bc2v[0] = (g==0) ? bc2[0] : 0.f;
    bc2v[1] = (g==0) ? bc2[1] : 0.f;
    bc2v[2] = 0.f; bc2v[3] = 0.f;

    __syncthreads();

    unsigned* BW = &bounce[wid][0];
    const int wbase = c*8 + g*2;                         // write word base
    const int rbase = (g>>1)*128 + c*8 + (g&1)*4;        // read word base
    auto SL = [&](int s)->bf16x8 {
        return *reinterpret_cast<const bf16x8*>(&stash[(s*64 + lane)*4]);
    };
    auto RD = [&](int kt, int nt)->bf16x8 {
        return *reinterpret_cast<const bf16x8*>(&BW[rbase + (nt*4 + kt*2)*128]);
    };

    const int gwave = blockIdx.x*4 + wid;

    #pragma unroll 1
    for (int tt = 0; tt < 6; ++tt) {
        const int tile = gwave*6 + tt;          // 0..49151
        const int n  = tile / 12;               // ray (wave-uniform)
        const int s0 = (tile - n*12) * 64;
        const int s  = s0 + lane;               // this lane's sample (step idx)

        const float z  = 0.01f + 0.8f * ((float)s * (1.0f/767.0f));
        const float ox = rays_o[3*n+0], oy = rays_o[3*n+1], oz = rays_o[3*n+2];
        const float dx = rays_d[3*n+0], dy = rays_d[3*n+1], dz = rays_d[3*n+2];
        const float tm = timev[n];

        const float px = fminf(fmaxf(fmaf(dx, z, ox), -1.f), 1.f);
        const float py = fminf(fmaxf(fmaf(dy, z, oy), -1.f), 1.f);
        const float pz = fminf(fmaxf(fmaf(dz, z, oz), -1.f), 1.f);
        const unsigned p01 = cvt_pk_bf16(px, py);
        const unsigned p23 = cvt_pk_bf16(pz, tm);

        f32x4 acc[4][4];

        // ---------------- GEMM1: W1ext^T @ X^T (K=32, bias at k=4) --------
        {
            bf16x8 a1[4];
            #pragma unroll
            for (int ft = 0; ft < 4; ++ft) a1[ft] = SL(ft);
            __builtin_amdgcn_s_setprio(1);
            #pragma unroll
            for (int nt = 0; nt < 4; ++nt) {
                unsigned q0 = (unsigned)__shfl((int)p01, nt*16 + c);
                unsigned q1 = (unsigned)__shfl((int)p23, nt*16 + c);
                union { bf16x8 v; unsigned u[4]; } b;
                b.u[0] = (g==0) ? q0 : 0u;
                b.u[1] = (g==0) ? q1 : 0u;
                b.u[2] = (g==0) ? 0x00003F80u : 0u;   // bf16 1.0 at k=4
                b.u[3] = 0u;
                #pragma unroll
                for (int ft = 0; ft < 4; ++ft)
                    acc[ft][nt] = __builtin_amdgcn_mfma_f32_16x16x32_bf16(
                        a1[ft], b.v, zero4(), 0, 0, 0);
            }
            __builtin_amdgcn_s_setprio(0);
        }
        // relu + bounce h1
        ldsfence();
        #pragma unroll
        for (int ft = 0; ft < 4; ++ft)
            #pragma unroll
            for (int nt = 0; nt < 4; ++nt) {
                unsigned pk0 = pk_relu_bf16x2(cvt_pk_bf16(acc[ft][nt][0], acc[ft][nt][1]));
                unsigned pk1 = pk_relu_bf16x2(cvt_pk_bf16(acc[ft][nt][2], acc[ft][nt][3]));
                *reinterpret_cast<uint2*>(&BW[wbase + (nt*4+ft)*128]) = make_uint2(pk0, pk1);
            }
        ldsfence();

        // ---------------- GEMM2: W2^T @ h1 (C-init = b2) -------------------
        {
            f32x4 b2v[4];
            #pragma unroll
            for (int ft = 0; ft < 4; ++ft)
                b2v[ft] = *reinterpret_cast<const f32x4*>(&stash[((12+ft)*64 + lane)*4]);
            __builtin_amdgcn_s_setprio(1);
            #pragma unroll
            for (int nt = 0; nt < 4; ++nt) {
                bf16x8 f0 = RD(0, nt), f1 = RD(1, nt);
                #pragma unroll
                for (int ft = 0; ft < 4; ++ft) {
                    f32x4 d = __builtin_amdgcn_mfma_f32_16x16x32_bf16(bW2A[0][ft], f0, b2v[ft], 0,0,0);
                    acc[ft][nt] = __builtin_amdgcn_mfma_f32_16x16x32_bf16(bW2A[1][ft], f1, d, 0,0,0);
                }
            }
            __builtin_amdgcn_s_setprio(0);
        }
        // relu + bounce h2
        ldsfence();
        #pragma unroll
        for (int ft = 0; ft < 4; ++ft)
            #pragma unroll
            for (int nt = 0; nt < 4; ++nt) {
                unsigned pk0 = pk_relu_bf16x2(cvt_pk_bf16(acc[ft][nt][0], acc[ft][nt][1]));
                unsigned pk1 = pk_relu_bf16x2(cvt_pk_bf16(acc[ft][nt][2], acc[ft][nt][3]));
                *reinterpret_cast<uint2*>(&BW[wbase + (nt*4+ft)*128]) = make_uint2(pk0, pk1);
            }
        ldsfence();

        // -------- GEMM3: Wc1^T @ [h2; dirs; 1] (3 k-steps) + sigma ---------
        f32x4 sigD[4];
        {
            bf16x8 ad[4];
            #pragma unroll
            for (int ft = 0; ft < 4; ++ft) ad[ft] = SL(4+ft);
            bf16x8 ws0 = SL(8), ws1 = SL(9);
            union { bf16x8 v; unsigned u[4]; } fd;
            fd.u[0] = (g==0) ? cvt_pk_bf16(dx, dy) : 0u;
            fd.u[1] = (g==0) ? cvt_pk_bf16(dz, 1.0f) : 0u;
            fd.u[2] = 0u; fd.u[3] = 0u;
            __builtin_amdgcn_s_setprio(1);
            #pragma unroll
            for (int nt = 0; nt < 4; ++nt) {
                bf16x8 f0 = RD(0, nt), f1 = RD(1, nt);
                #pragma unroll
                for (int ft = 0; ft < 4; ++ft) {
                    f32x4 d = __builtin_amdgcn_mfma_f32_16x16x32_bf16(bWc1A[0][ft], f0, zero4(), 0,0,0);
                    d = __builtin_amdgcn_mfma_f32_16x16x32_bf16(bWc1A[1][ft], f1, d, 0,0,0);
                    acc[ft][nt] = __builtin_amdgcn_mfma_f32_16x16x32_bf16(ad[ft], fd.v, d, 0,0,0);
                }
                f32x4 sd = __builtin_amdgcn_mfma_f32_16x16x32_bf16(ws0, f0, zero4(), 0,0,0);
                sigD[nt] = __builtin_amdgcn_mfma_f32_16x16x32_bf16(ws1, f1, sd, 0,0,0);
            }
            __builtin_amdgcn_s_setprio(0);
        }
        // relu + bounce cfeat
        ldsfence();
        #pragma unroll
        for (int ft = 0; ft < 4; ++ft)
            #pragma unroll
            for (int nt = 0; nt < 4; ++nt) {
                unsigned pk0 = pk_relu_bf16x2(cvt_pk_bf16(acc[ft][nt][0], acc[ft][nt][1]));
                unsigned pk1 = pk_relu_bf16x2(cvt_pk_bf16(acc[ft][nt][2], acc[ft][nt][3]));
                *reinterpret_cast<uint2*>(&BW[wbase + (nt*4+ft)*128]) = make_uint2(pk0, pk1);
            }
        ldsfence();

        // sigma redistribute (row 0 lives in lanes g==0, reg 0) + alpha
        {
            float v0 = __shfl(sigD[0][0], c);
            float v1 = __shfl(sigD[1][0], c);
            float v2 = __shfl(sigD[2][0], c);
            float v3 = __shfl(sigD[3][0], c);
            float pre = (g==0) ? v0 : ((g==1) ? v1 : ((g==2) ? v2 : v3));
            pre += bsg;
            float sig = fmaxf(pre, 0.f) + __logf(1.f + __expf(-fabsf(pre)));
            float dl  = (s == NS-1) ? (0.8f/768.0f) : (0.8f/767.0f);
            alpha_out[tile*64 + lane] = 1.0f - __expf(-dl * sig);
        }

        // ---------------- GEMM4: Wc2^T @ cfeat (rows 0,1) ------------------
        {
            bf16x8 c20 = SL(10), c21 = SL(11);
            f32x4 rgbD[4];
            __builtin_amdgcn_s_setprio(1);
            #pragma unroll
            for (int nt = 0; nt < 4; ++nt) {
                bf16x8 f0 = RD(0, nt), f1 = RD(1, nt);
                f32x4 d = __builtin_amdgcn_mfma_f32_16x16x32_bf16(c20, f0, bc2v, 0,0,0);
                rgbD[nt] = __builtin_amdgcn_mfma_f32_16x16x32_bf16(c21, f1, d, 0,0,0);
            }
            __builtin_amdgcn_s_setprio(0);
            ldsfence();
            float a0 = __shfl(rgbD[0][0], c), b0 = __shfl(rgbD[0][1], c);
            float a1 = __shfl(rgbD[1][0], c), b1v_ = __shfl(rgbD[1][1], c);
            float a2 = __shfl(rgbD[2][0], c), b2_ = __shfl(rgbD[2][1], c);
            float a3 = __shfl(rgbD[3][0], c), b3 = __shfl(rgbD[3][1], c);
            float r0 = (g==0) ? a0 : ((g==1) ? a1 : ((g==2) ? a2 : a3));
            float r1 = (g==0) ? b0 : ((g==1) ? b1v_ : ((g==2) ? b2_ : b3));
            r0 = 1.0f / (1.0f + __expf(-r0));
            r1 = 1.0f / (1.0f + __expf(-r1));
            rgb_out[tile*64 + lane] = cvt_pk_bf16(r0, r1);   // packed 2xbf16
        }
    }
}

// ---------------------------------------------------------------------------
// Kernel 2: wave-per-ray compositing; rgb now packed 2xbf16 (half traffic)
// ---------------------------------------------------------------------------
__global__ __launch_bounds__(256) void composite_kernel(
    const unsigned* __restrict__ rgb,   // [NR][NS] packed {r0,r1} bf16
    float* __restrict__ out)
{
    int gtid = blockIdx.x * 256 + threadIdx.x;
    int ray  = gtid >> 6;
    int lane = threadIdx.x & 63;
    if (ray >= NR) return;

    float* __restrict__ depth_o = out;
    float* __restrict__ image_o = out + OFF_IMAGE;
    float* __restrict__ wsum_o  = out + OFF_WSUM;
    float* __restrict__ w_o     = out + OFF_WEIGHTS;   // alpha in, weights out
    float* __restrict__ z_o     = out + OFF_ZVALS;

    float T = 1.0f;
    float depth = 0.0f, wsum = 0.0f, im0 = 0.0f, im1 = 0.0f;

    for (int ch = 0; ch < NS/64; ++ch) {
        int s   = ch*64 + lane;
        int idx = ray*NS + s;
        float a  = w_o[idx];
        float zv = 0.01f + 0.8f * ((float)s * (1.0f/767.0f));
        float f  = 1.0f - a + 1e-15f;

        float p = f;
        #pragma unroll
        for (int off = 1; off < 64; off <<= 1) {
            float v = __shfl_up(p, off, 64);
            if (lane >= off) p *= v;
        }
        float excl = __shfl_up(p, 1, 64);
        if (lane == 0) excl = 1.0f;

        float wgt = a * T * excl;

        unsigned pv = rgb[idx];
        float r0 = bf2f((unsigned short)(pv & 0xffffu));
        float r1 = bf2f((unsigned short)(pv >> 16));
        depth = fmaf(wgt, zv, depth);
        wsum += wgt;
        im0   = fmaf(wgt, r0, im0);
        im1   = fmaf(wgt, r1, im1);

        w_o[idx] = wgt;
        z_o[idx] = zv;

        T *= __shfl(p, 63, 64);
    }

    #pragma unroll
    for (int off = 32; off >= 1; off >>= 1) {
        depth += __shfl_down(depth, off, 64);
        wsum  += __shfl_down(wsum , off, 64);
        im0   += __shfl_down(im0  , off, 64);
        im1   += __shfl_down(im1  , off, 64);
    }
    if (lane == 0) {
        depth_o[ray]      = depth;
        image_o[2*ray+0]  = im0;
        image_o[2*ray+1]  = im1;
        wsum_o[ray]       = wsum;
    }
}

extern "C" void kernel_launch(void* const* d_in, const int* in_sizes, int n_in,
                              void* d_out, int out_size, void* d_ws, size_t ws_size,
                              hipStream_t stream) {
    const float* rays_o = (const float*)d_in[0];
    const float* rays_d = (const float*)d_in[1];
    const float* timev  = (const float*)d_in[2];
    const float* W1     = (const float*)d_in[3];
    const float* b1     = (const float*)d_in[4];
    const float* W2     = (const float*)d_in[5];
    const float* b2     = (const float*)d_in[6];
    const float* w_sig  = (const float*)d_in[7];
    const float* b_sig  = (const float*)d_in[8];
    const float* Wc1    = (const float*)d_in[9];
    const float* bc1    = (const float*)d_in[10];
    const float* Wc2    = (const float*)d_in[11];
    const float* bc2    = (const float*)d_in[12];

    float* out     = (float*)d_out;
    float* alpha   = out + OFF_WEIGHTS;     // stash alpha in the weights slot
    unsigned* rgb  = (unsigned*)d_ws;       // [NR*NS] packed 2xbf16

    dim3 blk(256);
    // 2048 blocks * 4 waves * 6 tiles * 64 samples = 4096*768 samples
    hipLaunchKernelGGL(mlp_mfma_kernel, dim3(2048), blk, 0, stream,
                       rays_o, rays_d, timev, W1, b1, W2, b2, w_sig, b_sig,
                       Wc1, bc1, Wc2, bc2, alpha, rgb);

    hipLaunchKernelGGL(composite_kernel, dim3((NR*64)/256), blk, 0, stream, rgb, out);
}

// Round 14
// 112.061 us; speedup vs baseline: 1.2879x; 1.2391x over previous
//
#include <hip/hip_runtime.h>
#include <hip/hip_bf16.h>
#include <math.h>

#define NR 4096
#define NS 768

// Outputs (flat, fp32): depth[4096] | image[4096*2] | wsum[4096] | weights[4096*768] | z_vals[4096*768]
#define OFF_IMAGE   (NR)
#define OFF_WSUM    (NR*3)
#define OFF_WEIGHTS (NR*4)
#define OFF_ZVALS   (NR*4 + NR*NS)

typedef short bf16x8 __attribute__((ext_vector_type(8)));
typedef float f32x4  __attribute__((ext_vector_type(4)));

static __device__ __forceinline__ unsigned cvt_pk_bf16(float a, float b){
    unsigned r;
    asm("v_cvt_pk_bf16_f32 %0, %1, %2" : "=v"(r) : "v"(a), "v"(b));
    return r;
}
static __device__ __forceinline__ f32x4 zero4(){ f32x4 r = {0.f,0.f,0.f,0.f}; return r; }
// zero-instruction compiler fence (r10/r11-proven safe)
static __device__ __forceinline__ void ldsfence(){ asm volatile("" ::: "memory"); }

// ---------------------------------------------------------------------------
// r8-exact transposed full-tile MLP with ONE change: conflict-free bounce
// LAYOUT (no XOR). Logical (c, w) mapping identical to the r8-HW-proven one;
// physical bijection within each 128-word F-block changed from
//   old: c*8 + w        (read start-bank (c&3)*8 -> 8-way conflicts)
//   new: (w>>2)*64 + c*4 + (w&3)   (read start-bank (c&7)*4 -> conflict-free)
// Writer (g,c), w = g*2+i = (g>>1)*4+(g&1)*2+i:
//   word = F*128 + (g>>1)*64 + c*4 + (g&1)*2 + i   (uint2, 2-aligned)
// Reader (g,c), w = (g&1)*4+j:
//   word = F*128 + (g&1)*64 + c*4 + j              (b128, 4-aligned)
// ---------------------------------------------------------------------------
__global__ __launch_bounds__(256, 2) void mlp_mfma_kernel(
    const float* __restrict__ rays_o, const float* __restrict__ rays_d,
    const float* __restrict__ timev,
    const float* __restrict__ W1, const float* __restrict__ b1,
    const float* __restrict__ W2, const float* __restrict__ b2,
    const float* __restrict__ w_sig, const float* __restrict__ b_sig,
    const float* __restrict__ Wc1, const float* __restrict__ bc1,
    const float* __restrict__ Wc2, const float* __restrict__ bc2,
    float* __restrict__ alpha_out,   // [NR*NS] (aliases weights slot of d_out)
    float* __restrict__ rgb_out)     // [NR*NS][2] fp32 in d_ws
{
    __shared__ __align__(16) unsigned bounce[4][2048];     // 8 KB per wave
    __shared__ __align__(16) unsigned stash[16*64*4];      // 16 frag slots
    const int wid  = threadIdx.x >> 6;
    const int lane = threadIdx.x & 63;
    const int g = lane >> 4;          // 0..3
    const int c = lane & 15;          // 0..15

    // ---- stash (block-shared, built by wave 0) — r8-exact ----
    if (wid == 0) {
        #pragma unroll
        for (int ft = 0; ft < 4; ++ft) {
            const int col = ft*16 + c;
            unsigned u0=0,u1=0,u2=0,u3=0, d0=0,d1=0;
            if (g == 0) {
                u0 = cvt_pk_bf16(W1[0*64+col], W1[1*64+col]);
                u1 = cvt_pk_bf16(W1[2*64+col], W1[3*64+col]);
                u2 = cvt_pk_bf16(b1[col], 0.f);
                d0 = cvt_pk_bf16(Wc1[0*64+col], Wc1[1*64+col]);
                d1 = cvt_pk_bf16(Wc1[2*64+col], bc1[col]);
            }
            unsigned* p = &stash[(ft*64 + lane)*4];
            p[0]=u0; p[1]=u1; p[2]=u2; p[3]=u3;
            unsigned* q = &stash[((4+ft)*64 + lane)*4];
            q[0]=d0; q[1]=d1; q[2]=0; q[3]=0;
        }
        #pragma unroll
        for (int kt = 0; kt < 2; ++kt) {
            unsigned s[4], w[4];
            #pragma unroll
            for (int p = 0; p < 4; ++p) {
                int k = kt*32 + 8*g + 2*p;
                s[p] = (c == 0) ? cvt_pk_bf16(w_sig[k], w_sig[k+1]) : 0u;
                w[p] = (c < 2)  ? cvt_pk_bf16(Wc2[k*2+c], Wc2[(k+1)*2+c]) : 0u;
            }
            unsigned* ps = &stash[((8+kt)*64 + lane)*4];
            ps[0]=s[0]; ps[1]=s[1]; ps[2]=s[2]; ps[3]=s[3];
            unsigned* pw = &stash[((10+kt)*64 + lane)*4];
            pw[0]=w[0]; pw[1]=w[1]; pw[2]=w[2]; pw[3]=w[3];
        }
        #pragma unroll
        for (int ft = 0; ft < 4; ++ft) {
            float* pb = reinterpret_cast<float*>(&stash[((12+ft)*64 + lane)*4]);
            #pragma unroll
            for (int r = 0; r < 4; ++r) pb[r] = b2[ft*16 + g*4 + r];
        }
    }

    // ---- hot A-frags in registers — r8-exact ----
    auto ldfrag = [&](const float* __restrict__ W, int k0, int col)->bf16x8 {
        union { bf16x8 v; unsigned u[4]; } r;
        #pragma unroll
        for (int p = 0; p < 4; ++p) {
            int k = k0 + 2*p;
            r.u[p] = cvt_pk_bf16(W[k*64 + col], W[(k+1)*64 + col]);
        }
        return r.v;
    };
    bf16x8 bW2A[2][4], bWc1A[2][4];
    #pragma unroll
    for (int ft = 0; ft < 4; ++ft) {
        const int col = ft*16 + c;
        #pragma unroll
        for (int kt = 0; kt < 2; ++kt) {
            bW2A[kt][ft]  = ldfrag(W2,         kt*32 + 8*g, col);
            bWc1A[kt][ft] = ldfrag(Wc1 + 3*64, kt*32 + 8*g, col);
        }
    }
    const float bsg = b_sig[0];
    f32x4 bc2v;
    bc2v[0] = (g==0) ? bc2[0] : 0.f;
    bc2v[1] = (g==0) ? bc2[1] : 0.f;
    bc2v[2] = 0.f; bc2v[3] = 0.f;

    __syncthreads();

    unsigned* BW = &bounce[wid][0];
    // NEW conflict-free bijection (no XOR):
    const int wbase = (g>>1)*64 + c*4 + (g&1)*2;         // write word base
    const int rbase = (g>>1)*128 + (g&1)*64 + c*4;       // read word base (incl. F-part)
    auto SL = [&](int s)->bf16x8 {
        return *reinterpret_cast<const bf16x8*>(&stash[(s*64 + lane)*4]);
    };
    auto RD = [&](int kt, int nt)->bf16x8 {
        return *reinterpret_cast<const bf16x8*>(&BW[rbase + (nt*4 + kt*2)*128]);
    };

    const int gwave = blockIdx.x*4 + wid;

    #pragma unroll 1
    for (int tt = 0; tt < 6; ++tt) {
        const int tile = gwave*6 + tt;          // 0..49151
        const int n  = tile / 12;               // ray (wave-uniform)
        const int s0 = (tile - n*12) * 64;
        const int s  = s0 + lane;               // this lane's sample (step idx)

        const float z  = 0.01f + 0.8f * ((float)s * (1.0f/767.0f));
        const float ox = rays_o[3*n+0], oy = rays_o[3*n+1], oz = rays_o[3*n+2];
        const float dx = rays_d[3*n+0], dy = rays_d[3*n+1], dz = rays_d[3*n+2];
        const float tm = timev[n];

        const float px = fminf(fmaxf(fmaf(dx, z, ox), -1.f), 1.f);
        const float py = fminf(fmaxf(fmaf(dy, z, oy), -1.f), 1.f);
        const float pz = fminf(fmaxf(fmaf(dz, z, oz), -1.f), 1.f);
        const unsigned p01 = cvt_pk_bf16(px, py);
        const unsigned p23 = cvt_pk_bf16(pz, tm);

        f32x4 acc[4][4];

        // ---------------- GEMM1: W1ext^T @ X^T (K=32, bias at k=4) --------
        {
            bf16x8 a1[4];
            #pragma unroll
            for (int ft = 0; ft < 4; ++ft) a1[ft] = SL(ft);
            #pragma unroll
            for (int nt = 0; nt < 4; ++nt) {
                unsigned q0 = (unsigned)__shfl((int)p01, nt*16 + c);
                unsigned q1 = (unsigned)__shfl((int)p23, nt*16 + c);
                union { bf16x8 v; unsigned u[4]; } b;
                b.u[0] = (g==0) ? q0 : 0u;
                b.u[1] = (g==0) ? q1 : 0u;
                b.u[2] = (g==0) ? 0x00003F80u : 0u;   // bf16 1.0 at k=4
                b.u[3] = 0u;
                #pragma unroll
                for (int ft = 0; ft < 4; ++ft)
                    acc[ft][nt] = __builtin_amdgcn_mfma_f32_16x16x32_bf16(
                        a1[ft], b.v, zero4(), 0, 0, 0);
            }
        }
        // relu + bounce h1
        ldsfence();
        #pragma unroll
        for (int ft = 0; ft < 4; ++ft)
            #pragma unroll
            for (int nt = 0; nt < 4; ++nt) {
                unsigned pk0 = cvt_pk_bf16(fmaxf(acc[ft][nt][0],0.f), fmaxf(acc[ft][nt][1],0.f));
                unsigned pk1 = cvt_pk_bf16(fmaxf(acc[ft][nt][2],0.f), fmaxf(acc[ft][nt][3],0.f));
                *reinterpret_cast<uint2*>(&BW[wbase + (nt*4+ft)*128]) = make_uint2(pk0, pk1);
            }
        ldsfence();

        // ---------------- GEMM2: W2^T @ h1 (C-init = b2) -------------------
        {
            f32x4 b2v[4];
            #pragma unroll
            for (int ft = 0; ft < 4; ++ft)
                b2v[ft] = *reinterpret_cast<const f32x4*>(&stash[((12+ft)*64 + lane)*4]);
            #pragma unroll
            for (int nt = 0; nt < 4; ++nt) {
                bf16x8 f0 = RD(0, nt), f1 = RD(1, nt);
                #pragma unroll
                for (int ft = 0; ft < 4; ++ft) {
                    f32x4 d = __builtin_amdgcn_mfma_f32_16x16x32_bf16(bW2A[0][ft], f0, b2v[ft], 0,0,0);
                    acc[ft][nt] = __builtin_amdgcn_mfma_f32_16x16x32_bf16(bW2A[1][ft], f1, d, 0,0,0);
                }
            }
        }
        // relu + bounce h2
        ldsfence();
        #pragma unroll
        for (int ft = 0; ft < 4; ++ft)
            #pragma unroll
            for (int nt = 0; nt < 4; ++nt) {
                unsigned pk0 = cvt_pk_bf16(fmaxf(acc[ft][nt][0],0.f), fmaxf(acc[ft][nt][1],0.f));
                unsigned pk1 = cvt_pk_bf16(fmaxf(acc[ft][nt][2],0.f), fmaxf(acc[ft][nt][3],0.f));
                *reinterpret_cast<uint2*>(&BW[wbase + (nt*4+ft)*128]) = make_uint2(pk0, pk1);
            }
        ldsfence();

        // -------- GEMM3: Wc1^T @ [h2; dirs; 1] (3 k-steps) + sigma ---------
        f32x4 sigD[4];
        {
            bf16x8 ad[4];
            #pragma unroll
            for (int ft = 0; ft < 4; ++ft) ad[ft] = SL(4+ft);
            bf16x8 ws0 = SL(8), ws1 = SL(9);
            union { bf16x8 v; unsigned u[4]; } fd;
            fd.u[0] = (g==0) ? cvt_pk_bf16(dx, dy) : 0u;
            fd.u[1] = (g==0) ? cvt_pk_bf16(dz, 1.0f) : 0u;
            fd.u[2] = 0u; fd.u[3] = 0u;
            #pragma unroll
            for (int nt = 0; nt < 4; ++nt) {
                bf16x8 f0 = RD(0, nt), f1 = RD(1, nt);
                #pragma unroll
                for (int ft = 0; ft < 4; ++ft) {
                    f32x4 d = __builtin_amdgcn_mfma_f32_16x16x32_bf16(bWc1A[0][ft], f0, zero4(), 0,0,0);
                    d = __builtin_amdgcn_mfma_f32_16x16x32_bf16(bWc1A[1][ft], f1, d, 0,0,0);
                    acc[ft][nt] = __builtin_amdgcn_mfma_f32_16x16x32_bf16(ad[ft], fd.v, d, 0,0,0);
                }
                f32x4 sd = __builtin_amdgcn_mfma_f32_16x16x32_bf16(ws0, f0, zero4(), 0,0,0);
                sigD[nt] = __builtin_amdgcn_mfma_f32_16x16x32_bf16(ws1, f1, sd, 0,0,0);
            }
        }
        // relu + bounce cfeat
        ldsfence();
        #pragma unroll
        for (int ft = 0; ft < 4; ++ft)
            #pragma unroll
            for (int nt = 0; nt < 4; ++nt) {
                unsigned pk0 = cvt_pk_bf16(fmaxf(acc[ft][nt][0],0.f), fmaxf(acc[ft][nt][1],0.f));
                unsigned pk1 = cvt_pk_bf16(fmaxf(acc[ft][nt][2],0.f), fmaxf(acc[ft][nt][3],0.f));
                *reinterpret_cast<uint2*>(&BW[wbase + (nt*4+ft)*128]) = make_uint2(pk0, pk1);
            }
        ldsfence();

        // sigma redistribute (row 0 lives in lanes g==0, reg 0) + alpha
        {
            float v0 = __shfl(sigD[0][0], c);
            float v1 = __shfl(sigD[1][0], c);
            float v2 = __shfl(sigD[2][0], c);
            float v3 = __shfl(sigD[3][0], c);
            float pre = (g==0) ? v0 : ((g==1) ? v1 : ((g==2) ? v2 : v3));
            pre += bsg;
            float sig = fmaxf(pre, 0.f) + __logf(1.f + __expf(-fabsf(pre)));
            float dl  = (s == NS-1) ? (0.8f/768.0f) : (0.8f/767.0f);
            alpha_out[tile*64 + lane] = 1.0f - __expf(-dl * sig);
        }

        // ---------------- GEMM4: Wc2^T @ cfeat (rows 0,1) ------------------
        {
            bf16x8 c20 = SL(10), c21 = SL(11);
            f32x4 rgbD[4];
            #pragma unroll
            for (int nt = 0; nt < 4; ++nt) {
                bf16x8 f0 = RD(0, nt), f1 = RD(1, nt);
                f32x4 d = __builtin_amdgcn_mfma_f32_16x16x32_bf16(c20, f0, bc2v, 0,0,0);
                rgbD[nt] = __builtin_amdgcn_mfma_f32_16x16x32_bf16(c21, f1, d, 0,0,0);
            }
            ldsfence();
            float a0 = __shfl(rgbD[0][0], c), b0 = __shfl(rgbD[0][1], c);
            float a1 = __shfl(rgbD[1][0], c), b1v_ = __shfl(rgbD[1][1], c);
            float a2 = __shfl(rgbD[2][0], c), b2_ = __shfl(rgbD[2][1], c);
            float a3 = __shfl(rgbD[3][0], c), b3 = __shfl(rgbD[3][1], c);
            float r0 = (g==0) ? a0 : ((g==1) ? a1 : ((g==2) ? a2 : a3));
            float r1 = (g==0) ? b0 : ((g==1) ? b1v_ : ((g==2) ? b2_ : b3));
            r0 = 1.0f / (1.0f + __expf(-r0));
            r1 = 1.0f / (1.0f + __expf(-r1));
            *reinterpret_cast<float2*>(&rgb_out[2*(tile*64 + lane)]) = make_float2(r0, r1);
        }
    }
}

// ---------------------------------------------------------------------------
// Kernel 2: wave-per-ray compositing (r8-exact, proven correct)
// ---------------------------------------------------------------------------
__global__ __launch_bounds__(256) void composite_kernel(
    const float* __restrict__ rgb,   // [NR][NS][2]
    float* __restrict__ out)
{
    int gtid = blockIdx.x * 256 + threadIdx.x;
    int ray  = gtid >> 6;
    int lane = threadIdx.x & 63;
    if (ray >= NR) return;

    float* __restrict__ depth_o = out;
    float* __restrict__ image_o = out + OFF_IMAGE;
    float* __restrict__ wsum_o  = out + OFF_WSUM;
    float* __restrict__ w_o     = out + OFF_WEIGHTS;   // alpha in, weights out
    float* __restrict__ z_o     = out + OFF_ZVALS;

    float T = 1.0f;
    float depth = 0.0f, wsum = 0.0f, im0 = 0.0f, im1 = 0.0f;

    for (int ch = 0; ch < NS/64; ++ch) {
        int s   = ch*64 + lane;
        int idx = ray*NS + s;
        float a  = w_o[idx];
        float zv = 0.01f + 0.8f * ((float)s * (1.0f/767.0f));
        float f  = 1.0f - a + 1e-15f;

        float p = f;
        #pragma unroll
        for (int off = 1; off < 64; off <<= 1) {
            float v = __shfl_up(p, off, 64);
            if (lane >= off) p *= v;
        }
        float excl = __shfl_up(p, 1, 64);
        if (lane == 0) excl = 1.0f;

        float wgt = a * T * excl;

        float r0 = rgb[2*idx + 0], r1 = rgb[2*idx + 1];
        depth = fmaf(wgt, zv, depth);
        wsum += wgt;
        im0   = fmaf(wgt, r0, im0);
        im1   = fmaf(wgt, r1, im1);

        w_o[idx] = wgt;
        z_o[idx] = zv;

        T *= __shfl(p, 63, 64);
    }

    #pragma unroll
    for (int off = 32; off >= 1; off >>= 1) {
        depth += __shfl_down(depth, off, 64);
        wsum  += __shfl_down(wsum , off, 64);
        im0   += __shfl_down(im0  , off, 64);
        im1   += __shfl_down(im1  , off, 64);
    }
    if (lane == 0) {
        depth_o[ray]      = depth;
        image_o[2*ray+0]  = im0;
        image_o[2*ray+1]  = im1;
        wsum_o[ray]       = wsum;
    }
}

extern "C" void kernel_launch(void* const* d_in, const int* in_sizes, int n_in,
                              void* d_out, int out_size, void* d_ws, size_t ws_size,
                              hipStream_t stream) {
    const float* rays_o = (const float*)d_in[0];
    const float* rays_d = (const float*)d_in[1];
    const float* timev  = (const float*)d_in[2];
    const float* W1     = (const float*)d_in[3];
    const float* b1     = (const float*)d_in[4];
    const float* W2     = (const float*)d_in[5];
    const float* b2     = (const float*)d_in[6];
    const float* w_sig  = (const float*)d_in[7];
    const float* b_sig  = (const float*)d_in[8];
    const float* Wc1    = (const float*)d_in[9];
    const float* bc1    = (const float*)d_in[10];
    const float* Wc2    = (const float*)d_in[11];
    const float* bc2    = (const float*)d_in[12];

    float* out   = (float*)d_out;
    float* alpha = out + OFF_WEIGHTS;      // stash alpha in the weights slot
    float* rgb   = (float*)d_ws;           // [NR][NS][2] fp32

    dim3 blk(256);
    // 2048 blocks * 4 waves * 6 tiles * 64 samples = 4096*768 samples
    hipLaunchKernelGGL(mlp_mfma_kernel, dim3(2048), blk, 0, stream,
                       rays_o, rays_d, timev, W1, b1, W2, b2, w_sig, b_sig,
                       Wc1, bc1, Wc2, bc2, alpha, rgb);

    hipLaunchKernelGGL(composite_kernel, dim3((NR*64)/256), blk, 0, stream, rgb, out);
}